// Round 8
// baseline (553.449 us; speedup 1.0000x reference)
//
#include <hip/hip_runtime.h>

// Problem constants
#define BATCH 4096
#define FEATS 26
#define BAG   8
#define EDIM  64
#define INDIM 1664   // 26*64

typedef short bf16x8 __attribute__((ext_vector_type(8)));
typedef float f32x4  __attribute__((ext_vector_type(4)));
typedef unsigned short u16x8 __attribute__((ext_vector_type(8)));

__device__ __forceinline__ unsigned short f2bf(float f) {
    unsigned u = __float_as_uint(f);
    unsigned r = (u + 0x7FFFu + ((u >> 16) & 1u)) >> 16;
    return (unsigned short)r;
}
__device__ __forceinline__ float bf2f(unsigned short h) {
    return __uint_as_float((unsigned)h << 16);
}
// async global->LDS, 16B per lane. HW dst = wave-uniform base + lane*16.
__device__ __forceinline__ void async_cp16(const void* g, void* lds_base_uniform) {
    __builtin_amdgcn_global_load_lds(
        (const __attribute__((address_space(1))) unsigned int*)g,
        (__attribute__((address_space(3))) unsigned int*)lds_base_uniform,
        16, 0, 0);
}
// s_waitcnt with only vmcnt constrained (lgkm=15, exp=7 i.e. no wait)
#define WAITCNT_VM(n) __builtin_amdgcn_s_waitcnt(0x0F70 | (n))

// ---------------- batched weight transpose + fp32->bf16 (1 launch, 6 weights) ----
__global__ __launch_bounds__(256) void transpose_all(
    const float* __restrict__ w10, unsigned short* __restrict__ o10,
    const float* __restrict__ w20, unsigned short* __restrict__ o20,
    const float* __restrict__ w11, unsigned short* __restrict__ o11,
    const float* __restrict__ w21, unsigned short* __restrict__ o21,
    const float* __restrict__ w12, unsigned short* __restrict__ o12,
    const float* __restrict__ w22, unsigned short* __restrict__ o22)
{
    const float* in; unsigned short* out; int R, C;
    switch (blockIdx.z) {
        case 0:  in = w10; out = o10; R = INDIM; C = 1024;  break;
        case 1:  in = w20; out = o20; R = 1024;  C = INDIM; break;
        case 2:  in = w11; out = o11; R = INDIM; C = 1024;  break;
        case 3:  in = w21; out = o21; R = 1024;  C = INDIM; break;
        case 4:  in = w12; out = o12; R = INDIM; C = 512;   break;
        default: in = w22; out = o22; R = 512;   C = INDIM; break;
    }
    const int c0 = blockIdx.x * 64, r0 = blockIdx.y * 64;
    if (c0 >= C || r0 >= R) return;

    __shared__ unsigned short tile[64][65];
    const int t = threadIdx.x;
    const int tc = t & 63, tr = t >> 6;
#pragma unroll
    for (int i = 0; i < 16; ++i) {
        int r = tr + i * 4;
        tile[r][tc] = f2bf(in[(long long)(r0 + r) * C + c0 + tc]);
    }
    __syncthreads();
    const int wr = t >> 3, wc = t & 7;
#pragma unroll
    for (int half = 0; half < 2; ++half) {
        int row = wr + half * 32;
        u16x8 v;
#pragma unroll
        for (int j = 0; j < 8; ++j) v[j] = tile[wc * 8 + j][row];
        *(u16x8*)(out + (long long)(c0 + row) * R + r0 + wc * 8) = v;
    }
}

// ---------------- embedding bag: 2 bags/wave (16 outstanding gathers) ----------
__global__ __launch_bounds__(256) void embed_pool(
    const int* __restrict__ x, const float* __restrict__ emb,
    unsigned short* __restrict__ feat)
{
    const int wave = threadIdx.x >> 6, lane = threadIdx.x & 63;
    const int bag0 = (blockIdx.x * 4 + wave) * 2;
    const int* xs = x + (long long)bag0 * BAG;
    float s0 = 0.f, s1 = 0.f;
#pragma unroll
    for (int l = 0; l < BAG; ++l) {
        int id0 = xs[l];
        int id1 = xs[BAG + l];
        s0 += emb[(long long)id0 * EDIM + lane];
        s1 += emb[(long long)id1 * EDIM + lane];
    }
#pragma unroll
    for (int g = 0; g < 2; ++g) {
        int bag = bag0 + g;
        int b = bag / FEATS, f = bag - b * FEATS;
        feat[(long long)b * INDIM + f * EDIM + lane] = f2bf(g ? s1 : s0);
    }
}

// ------------- bf16 MFMA GEMM: 128xBN tile, BK=32, NBUF=8, paired K-subtiles ----
// 512 threads = 8 waves, wave tile 64x(BN/4). Two K-subtiles per vmcnt+barrier
// -> 26 syncs for K=1664 instead of 52 (at 1 block/CU the barrier drain has
// nothing to hide behind; halving sync count attacks it directly; LDS is free
// since occupancy is grid-capped at 1 block/CU anyway). NBUF=8 (128KB): the
// ISSUE at pair p overwrites the buffer of tile 2p-4, computed TWO barriers
// earlier (NBUF=6 would race by one barrier).
// BN=64 (for N=512 GEMM -> full 256-block grid): waves 4-7 duplicate waves
// 0-3's B staging to the same LDS addresses (same data, benign) so per-wave
// cp16 count stays uniform (2/tile) and the counted vmcnt stays valid.
// XCD-grouping tile swizzle (R7, proven +): chunk q=nwg/8 consecutive tiles
// per XCD -> per-XCD L2 working set ~A 4-panels + B panel set.
// LDS XOR swizzle: slot (row, s) holds global k-chunk s ^ ((row>>1)&3) (16B).
#define NBUF 8
template<int BN>
__global__ __launch_bounds__(512) void gemm_bf16(
    const unsigned short* __restrict__ A, const unsigned short* __restrict__ Wt,
    const float* __restrict__ bias, const unsigned short* __restrict__ res,
    unsigned short* __restrict__ out, int M, int N, int K, int do_relu)
{
    constexpr int JN = BN / 64;              // col fragments per wave (2 or 1)

    __shared__ unsigned short As[NBUF * 128 * 32];
    __shared__ unsigned short Bs[NBUF * BN * 32];

    const int t = threadIdx.x;
    // ---- XCD-grouping tile swizzle (nwg % 8 == 0 for all grids here) ----
    const int nxg = gridDim.x;
    const int lin = blockIdx.y * nxg + blockIdx.x;
    const int q   = (nxg * gridDim.y) >> 3;
    const int tile = (lin & 7) * q + (lin >> 3);
    const int ty  = tile / nxg;
    const int bCol = (tile - ty * nxg) * BN;
    const int bRow = ty * 128;

    const int wave = t >> 6, lane = t & 63;
    const int wm = wave & 1, wn = wave >> 1;       // wn in 0..3
    const int lm = lane & 15, quad = lane >> 4;

    const int srow = lane >> 2;
    const int sq   = (lane & 3) ^ ((lane >> 3) & 3);
    const int slot = (quad ^ ((lm >> 1) & 3)) * 8;

    const int bwave = (BN == 128) ? wave : (wave & 3);
    const unsigned short* Ag = A  + (long long)(bRow + wave * 16 + srow) * K + sq * 8;
    const unsigned short* Bg = Wt + (long long)(bCol + bwave * 16 + srow) * K + sq * 8;
    unsigned short* AsW = As + wave * 512;    // + buf*4096
    unsigned short* BsW = Bs + bwave * 512;   // + buf*(BN*32)

    const int T = K / 32;                     // even for all shapes here
    const int P = T / 2;
    f32x4 acc[4][JN] = {};

#define ISSUE(tile_)  do { int _b = (tile_) & (NBUF - 1);                         \
        async_cp16(Ag + (long long)(tile_) * 32, AsW + _b * 4096);                \
        async_cp16(Bg + (long long)(tile_) * 32, BsW + _b * (BN * 32)); } while (0)

#define COMPUTE(tile_) do { int _b = (tile_) & (NBUF - 1);                        \
        const unsigned short* _a = As + _b * 4096;                                \
        const unsigned short* _bp = Bs + _b * (BN * 32);                          \
        bf16x8 af[4], bf[JN];                                                     \
        _Pragma("unroll")                                                         \
        for (int i = 0; i < 4; ++i)                                               \
            af[i] = *(const bf16x8*)&_a[(wm * 64 + i * 16 + lm) * 32 + slot];     \
        _Pragma("unroll")                                                         \
        for (int j = 0; j < JN; ++j)                                              \
            bf[j] = *(const bf16x8*)&_bp[(wn * (BN / 4) + j * 16 + lm) * 32 + slot]; \
        _Pragma("unroll")                                                         \
        for (int i = 0; i < 4; ++i)                                               \
            _Pragma("unroll")                                                     \
            for (int j = 0; j < JN; ++j)                                          \
                acc[i][j] = __builtin_amdgcn_mfma_f32_16x16x32_bf16(              \
                    af[i], bf[j], acc[i][j], 0, 0, 0); } while (0)

    ISSUE(0); ISSUE(1); ISSUE(2); ISSUE(3);
    for (int p = 0; p < P - 2; ++p) {
        ISSUE(2 * p + 4);              // pair p+2; overwrites tiles of pair p-2
        ISSUE(2 * p + 5);              //   (computed two barriers ago: safe)
        WAITCNT_VM(8);                 // pair p's 4 cp16 complete (pairs p+1,p+2 in flight)
        asm volatile("" ::: "memory");
        __builtin_amdgcn_s_barrier();
        asm volatile("" ::: "memory");
        COMPUTE(2 * p);
        COMPUTE(2 * p + 1);
    }
    WAITCNT_VM(4);
    asm volatile("" ::: "memory");
    __builtin_amdgcn_s_barrier();
    asm volatile("" ::: "memory");
    COMPUTE(2 * P - 4);
    COMPUTE(2 * P - 3);
    WAITCNT_VM(0);
    asm volatile("" ::: "memory");
    __builtin_amdgcn_s_barrier();
    asm volatile("" ::: "memory");
    COMPUTE(2 * P - 2);
    COMPUTE(2 * P - 1);

    // ---- epilogue: bias (+res) (+relu), bf16 out ----
#pragma unroll
    for (int i = 0; i < 4; ++i) {
#pragma unroll
        for (int j = 0; j < JN; ++j) {
            int col = bCol + wn * (BN / 4) + j * 16 + lm;
            float bv = bias[col];
#pragma unroll
            for (int r = 0; r < 4; ++r) {
                int row = bRow + wm * 64 + i * 16 + quad * 4 + r;
                float v = acc[i][j][r] + bv;
                if (res) v += bf2f(res[(long long)row * N + col]);
                if (do_relu) v = fmaxf(v, 0.f);
                out[(long long)row * N + col] = f2bf(v);
            }
        }
    }
#undef ISSUE
#undef COMPUTE
}

// ---------------- final linear + sigmoid ----------------
__global__ __launch_bounds__(256) void final_head(
    const unsigned short* __restrict__ feat, const float* __restrict__ lin_w,
    const float* __restrict__ lin_b, float* __restrict__ out)
{
    int row  = blockIdx.x * 4 + (threadIdx.x >> 6);
    int lane = threadIdx.x & 63;
    const unsigned short* fr = feat + (long long)row * INDIM;
    float s = 0.f;
#pragma unroll
    for (int it = 0; it < INDIM / 64; ++it)
        s += bf2f(fr[it * 64 + lane]) * lin_w[it * 64 + lane];
#pragma unroll
    for (int off = 32; off; off >>= 1)
        s += __shfl_down(s, off, 64);
    if (lane == 0)
        out[row] = 1.f / (1.f + __expf(-(s + lin_b[0])));
}

extern "C" void kernel_launch(void* const* d_in, const int* in_sizes, int n_in,
                              void* d_out, int out_size, void* d_ws, size_t ws_size,
                              hipStream_t stream) {
    const int*   x    = (const int*)  d_in[0];
    const float* emb  = (const float*)d_in[1];
    const float* w1_0 = (const float*)d_in[2];
    const float* b1_0 = (const float*)d_in[3];
    const float* w2_0 = (const float*)d_in[4];
    const float* b2_0 = (const float*)d_in[5];
    const float* w1_1 = (const float*)d_in[6];
    const float* b1_1 = (const float*)d_in[7];
    const float* w2_1 = (const float*)d_in[8];
    const float* b2_1 = (const float*)d_in[9];
    const float* w1_2 = (const float*)d_in[10];
    const float* b1_2 = (const float*)d_in[11];
    const float* w2_2 = (const float*)d_in[12];
    const float* b2_2 = (const float*)d_in[13];
    const float* linw = (const float*)d_in[14];
    const float* linb = (const float*)d_in[15];
    float* out = (float*)d_out;

    // ws layout (bf16 elements)
    unsigned short* feat = (unsigned short*)d_ws;            // [4096,1664]
    unsigned short* h    = feat + (long long)BATCH * INDIM;  // [4096,1024]
    unsigned short* p    = h + (long long)BATCH * 1024;
    unsigned short* w1_0t = p; p += 1024 * INDIM;
    unsigned short* w2_0t = p; p += INDIM * 1024;
    unsigned short* w1_1t = p; p += 1024 * INDIM;
    unsigned short* w2_1t = p; p += INDIM * 1024;
    unsigned short* w1_2t = p; p += 512 * INDIM;
    unsigned short* w2_2t = p; p += INDIM * 512;

    // 0) all weight transposes in ONE launch (z = weight index)
    transpose_all<<<dim3(26, 26, 6), 256, 0, stream>>>(
        w1_0, w1_0t, w2_0, w2_0t, w1_1, w1_1t, w2_1, w2_1t, w1_2, w1_2t, w2_2, w2_2t);

    // 1) embedding bag -> bf16 feat (2 bags/wave)
    embed_pool<<<BATCH * FEATS / 8, 256, 0, stream>>>(x, emb, feat);

    // 2) residual blocks (XCD swizzle + paired-subtile pipeline)
    gemm_bf16<128><<<dim3(1024/128, BATCH/128), 512, 0, stream>>>(
        feat, w1_0t, b1_0, nullptr, h, BATCH, 1024, INDIM, 1);
    gemm_bf16<128><<<dim3(INDIM/128, BATCH/128), 512, 0, stream>>>(
        h, w2_0t, b2_0, feat, feat, BATCH, INDIM, 1024, 1);
    gemm_bf16<128><<<dim3(1024/128, BATCH/128), 512, 0, stream>>>(
        feat, w1_1t, b1_1, nullptr, h, BATCH, 1024, INDIM, 1);
    gemm_bf16<128><<<dim3(INDIM/128, BATCH/128), 512, 0, stream>>>(
        h, w2_1t, b2_1, feat, feat, BATCH, INDIM, 1024, 1);
    gemm_bf16<64><<<dim3(512/64, BATCH/128), 512, 0, stream>>>(
        feat, w1_2t, b1_2, nullptr, h, BATCH, 512, INDIM, 1);
    gemm_bf16<128><<<dim3(INDIM/128, BATCH/128), 512, 0, stream>>>(
        h, w2_2t, b2_2, feat, feat, BATCH, INDIM, 512, 1);

    // 3) head
    final_head<<<BATCH / 4, 256, 0, stream>>>(feat, linw, linb, out);
}

// Round 9
// 533.317 us; speedup vs baseline: 1.0377x; 1.0377x over previous
//
#include <hip/hip_runtime.h>

// Problem constants
#define BATCH 4096
#define FEATS 26
#define BAG   8
#define EDIM  64
#define INDIM 1664   // 26*64

typedef short bf16x8 __attribute__((ext_vector_type(8)));
typedef float f32x4  __attribute__((ext_vector_type(4)));
typedef unsigned short u16x8 __attribute__((ext_vector_type(8)));

__device__ __forceinline__ unsigned short f2bf(float f) {
    unsigned u = __float_as_uint(f);
    unsigned r = (u + 0x7FFFu + ((u >> 16) & 1u)) >> 16;
    return (unsigned short)r;
}
__device__ __forceinline__ float bf2f(unsigned short h) {
    return __uint_as_float((unsigned)h << 16);
}
// async global->LDS, 16B per lane. HW dst = wave-uniform base + lane*16.
__device__ __forceinline__ void async_cp16(const void* g, void* lds_base_uniform) {
    __builtin_amdgcn_global_load_lds(
        (const __attribute__((address_space(1))) unsigned int*)g,
        (__attribute__((address_space(3))) unsigned int*)lds_base_uniform,
        16, 0, 0);
}
// s_waitcnt with only vmcnt constrained (lgkm=15, exp=7 i.e. no wait)
#define WAITCNT_VM(n) __builtin_amdgcn_s_waitcnt(0x0F70 | (n))

// ---------------- batched weight transpose + fp32->bf16 (1 launch, 6 weights) ----
__global__ __launch_bounds__(256) void transpose_all(
    const float* __restrict__ w10, unsigned short* __restrict__ o10,
    const float* __restrict__ w20, unsigned short* __restrict__ o20,
    const float* __restrict__ w11, unsigned short* __restrict__ o11,
    const float* __restrict__ w21, unsigned short* __restrict__ o21,
    const float* __restrict__ w12, unsigned short* __restrict__ o12,
    const float* __restrict__ w22, unsigned short* __restrict__ o22)
{
    const float* in; unsigned short* out; int R, C;
    switch (blockIdx.z) {
        case 0:  in = w10; out = o10; R = INDIM; C = 1024;  break;
        case 1:  in = w20; out = o20; R = 1024;  C = INDIM; break;
        case 2:  in = w11; out = o11; R = INDIM; C = 1024;  break;
        case 3:  in = w21; out = o21; R = 1024;  C = INDIM; break;
        case 4:  in = w12; out = o12; R = INDIM; C = 512;   break;
        default: in = w22; out = o22; R = 512;   C = INDIM; break;
    }
    const int c0 = blockIdx.x * 64, r0 = blockIdx.y * 64;
    if (c0 >= C || r0 >= R) return;

    __shared__ unsigned short tile[64][65];
    const int t = threadIdx.x;
    const int tc = t & 63, tr = t >> 6;
#pragma unroll
    for (int i = 0; i < 16; ++i) {
        int r = tr + i * 4;
        tile[r][tc] = f2bf(in[(long long)(r0 + r) * C + c0 + tc]);
    }
    __syncthreads();
    const int wr = t >> 3, wc = t & 7;
#pragma unroll
    for (int half = 0; half < 2; ++half) {
        int row = wr + half * 32;
        u16x8 v;
#pragma unroll
        for (int j = 0; j < 8; ++j) v[j] = tile[wc * 8 + j][row];
        *(u16x8*)(out + (long long)(c0 + row) * R + r0 + wc * 8) = v;
    }
}

// ---------------- embedding bag (round-0 form) ----------------
__global__ __launch_bounds__(256) void embed_pool(
    const int* __restrict__ x, const float* __restrict__ emb,
    unsigned short* __restrict__ feat)
{
    int bag  = blockIdx.x * 4 + (threadIdx.x >> 6);
    int lane = threadIdx.x & 63;
    int b = bag / FEATS;
    int f = bag - b * FEATS;
    const int* xs = x + (long long)bag * BAG;
    float s = 0.f;
#pragma unroll
    for (int l = 0; l < BAG; ++l) {
        int id = xs[l];
        s += emb[(long long)id * EDIM + lane];
    }
    feat[(long long)b * INDIM + f * EDIM + lane] = f2bf(s);
}

// ------------- bf16 MFMA GEMM (R7 structure, best measured) -------------
// 128x128 tile, BK=32, 512 threads = 8 waves, wave tile 64x32, NBUF=4,
// counted vmcnt (loads stay in flight across barriers).
// XCD-grouping tile swizzle: chunk q=nwg/8 consecutive tiles per XCD
// (dispatch round-robins blocks across XCDs, lin&7 = XCD) -> per-XCD L2
// working set ~5MB -> A fetched ~once, B ~once per XCD (R7: -68us vs none).
// Split-K mode (part != nullptr): blockIdx.z selects K-half; acc written raw
// fp32 to part[z] buffer; bias/res/relu applied by reduce_split. Used for the
// N=512 GEMM whose full-K grid (128 blocks) leaves half the chip idle.
// LDS XOR swizzle: slot (row, s) holds global k-chunk s ^ ((row>>1)&3) (16B).
#define NBUF 4
__global__ __launch_bounds__(512) void gemm_bf16(
    const unsigned short* __restrict__ A, const unsigned short* __restrict__ Wt,
    const float* __restrict__ bias, const unsigned short* __restrict__ res,
    unsigned short* __restrict__ out, float* __restrict__ part,
    int M, int N, int K, int do_relu)
{
    __shared__ unsigned short As[NBUF * 128 * 32];
    __shared__ unsigned short Bs[NBUF * 128 * 32];

    const int t = threadIdx.x;
    // ---- XCD-grouping tile swizzle (nwg % 8 == 0 for all grids here) ----
    const int nxg = gridDim.x;
    const int lin = blockIdx.y * nxg + blockIdx.x;
    const int q   = (nxg * gridDim.y) >> 3;
    const int tile = (lin & 7) * q + (lin >> 3);
    const int ty  = tile / nxg;
    const int bCol = (tile - ty * nxg) * 128;
    const int bRow = ty * 128;

    // split-K: z picks K-half
    const int Keff = part ? (K >> 1) : K;
    const int kOff = part ? blockIdx.z * Keff : 0;

    const int wave = t >> 6, lane = t & 63;
    const int wm = wave & 1, wn = wave >> 1;       // wn in 0..3
    const int lm = lane & 15, quad = lane >> 4;

    const int srow = lane >> 2;
    const int sq   = (lane & 3) ^ ((lane >> 3) & 3);
    const unsigned short* Ag = A  + (long long)(bRow + wave * 16 + srow) * K + kOff + sq * 8;
    const unsigned short* Bg = Wt + (long long)(bCol + wave * 16 + srow) * K + kOff + sq * 8;
    unsigned short* AsW = As + wave * 512;   // + buf*4096
    unsigned short* BsW = Bs + wave * 512;

    const int T = Keff / 32;
    f32x4 acc[4][2] = {};
    const int slot = (quad ^ ((lm >> 1) & 3)) * 8;

#define ISSUE(tile_)  do { int _b = (tile_) & (NBUF - 1);                         \
        async_cp16(Ag + (long long)(tile_) * 32, AsW + _b * 4096);                \
        async_cp16(Bg + (long long)(tile_) * 32, BsW + _b * 4096); } while (0)

#define COMPUTE(tile_) do { int _b = (tile_) & (NBUF - 1);                        \
        const unsigned short* _a = As + _b * 4096;                                \
        const unsigned short* _bp = Bs + _b * 4096;                               \
        bf16x8 af[4], bf[2];                                                      \
        _Pragma("unroll")                                                         \
        for (int i = 0; i < 4; ++i)                                               \
            af[i] = *(const bf16x8*)&_a[(wm * 64 + i * 16 + lm) * 32 + slot];     \
        _Pragma("unroll")                                                         \
        for (int j = 0; j < 2; ++j)                                               \
            bf[j] = *(const bf16x8*)&_bp[(wn * 32 + j * 16 + lm) * 32 + slot];    \
        _Pragma("unroll")                                                         \
        for (int i = 0; i < 4; ++i)                                               \
            _Pragma("unroll")                                                     \
            for (int j = 0; j < 2; ++j)                                           \
                acc[i][j] = __builtin_amdgcn_mfma_f32_16x16x32_bf16(              \
                    af[i], bf[j], acc[i][j], 0, 0, 0); } while (0)

    ISSUE(0);
    ISSUE(1);
    for (int tt = 0; tt < T - 2; ++tt) {
        ISSUE(tt + 2);                 // lands in buf[(tt+2)&3] = buf[(tt-2)&3]: reads done
        WAITCNT_VM(4);                 // tile tt's 2 loads complete (t+1,t+2 still in flight)
        asm volatile("" ::: "memory");
        __builtin_amdgcn_s_barrier();
        asm volatile("" ::: "memory");
        COMPUTE(tt);
    }
    WAITCNT_VM(2);
    asm volatile("" ::: "memory");
    __builtin_amdgcn_s_barrier();
    asm volatile("" ::: "memory");
    COMPUTE(T - 2);
    WAITCNT_VM(0);
    asm volatile("" ::: "memory");
    __builtin_amdgcn_s_barrier();
    asm volatile("" ::: "memory");
    COMPUTE(T - 1);

    if (part) {
        // raw fp32 partials; reduce_split applies bias/relu/cvt
        float* po = part + (long long)blockIdx.z * M * N;
#pragma unroll
        for (int i = 0; i < 4; ++i)
#pragma unroll
            for (int j = 0; j < 2; ++j) {
                int col = bCol + wn * 32 + j * 16 + lm;
#pragma unroll
                for (int r = 0; r < 4; ++r) {
                    int row = bRow + wm * 64 + i * 16 + quad * 4 + r;
                    po[(long long)row * N + col] = acc[i][j][r];
                }
            }
    } else {
        // ---- epilogue: bias (+res) (+relu), bf16 out ----
#pragma unroll
        for (int i = 0; i < 4; ++i) {
#pragma unroll
            for (int j = 0; j < 2; ++j) {
                int col = bCol + wn * 32 + j * 16 + lm;
                float bv = bias[col];
#pragma unroll
                for (int r = 0; r < 4; ++r) {
                    int row = bRow + wm * 64 + i * 16 + quad * 4 + r;
                    float v = acc[i][j][r] + bv;
                    if (res) v += bf2f(res[(long long)row * N + col]);
                    if (do_relu) v = fmaxf(v, 0.f);
                    out[(long long)row * N + col] = f2bf(v);
                }
            }
        }
    }
#undef ISSUE
#undef COMPUTE
}

// ---------------- split-K reduce: p0+p1+bias, relu, -> bf16 ----------------
// N must divide 4; each thread handles 4 contiguous elements of a [M,N] grid.
__global__ __launch_bounds__(256) void reduce_split(
    const float* __restrict__ part, const float* __restrict__ bias,
    unsigned short* __restrict__ out, int M, int N)
{
    const long long total = (long long)M * N;
    long long i = ((long long)blockIdx.x * 256 + threadIdx.x) * 4;
    f32x4 a = *(const f32x4*)(part + i);
    f32x4 b = *(const f32x4*)(part + total + i);
    int col = (int)(i % N);
    u16x8 dummy; (void)dummy;
#pragma unroll
    for (int j = 0; j < 4; ++j) {
        float v = a[j] + b[j] + bias[col + j];
        v = fmaxf(v, 0.f);
        out[i + j] = f2bf(v);
    }
}

// ---------------- final linear + sigmoid ----------------
__global__ __launch_bounds__(256) void final_head(
    const unsigned short* __restrict__ feat, const float* __restrict__ lin_w,
    const float* __restrict__ lin_b, float* __restrict__ out)
{
    int row  = blockIdx.x * 4 + (threadIdx.x >> 6);
    int lane = threadIdx.x & 63;
    const unsigned short* fr = feat + (long long)row * INDIM;
    float s = 0.f;
#pragma unroll
    for (int it = 0; it < INDIM / 64; ++it)
        s += bf2f(fr[it * 64 + lane]) * lin_w[it * 64 + lane];
#pragma unroll
    for (int off = 32; off; off >>= 1)
        s += __shfl_down(s, off, 64);
    if (lane == 0)
        out[row] = 1.f / (1.f + __expf(-(s + lin_b[0])));
}

extern "C" void kernel_launch(void* const* d_in, const int* in_sizes, int n_in,
                              void* d_out, int out_size, void* d_ws, size_t ws_size,
                              hipStream_t stream) {
    const int*   x    = (const int*)  d_in[0];
    const float* emb  = (const float*)d_in[1];
    const float* w1_0 = (const float*)d_in[2];
    const float* b1_0 = (const float*)d_in[3];
    const float* w2_0 = (const float*)d_in[4];
    const float* b2_0 = (const float*)d_in[5];
    const float* w1_1 = (const float*)d_in[6];
    const float* b1_1 = (const float*)d_in[7];
    const float* w2_1 = (const float*)d_in[8];
    const float* b2_1 = (const float*)d_in[9];
    const float* w1_2 = (const float*)d_in[10];
    const float* b1_2 = (const float*)d_in[11];
    const float* w2_2 = (const float*)d_in[12];
    const float* b2_2 = (const float*)d_in[13];
    const float* linw = (const float*)d_in[14];
    const float* linb = (const float*)d_in[15];
    float* out = (float*)d_out;

    // ws layout (bf16 elements)
    unsigned short* feat = (unsigned short*)d_ws;            // [4096,1664]
    unsigned short* h    = feat + (long long)BATCH * INDIM;  // [4096,1024]
    unsigned short* p    = h + (long long)BATCH * 1024;
    unsigned short* w1_0t = p; p += 1024 * INDIM;
    unsigned short* w2_0t = p; p += INDIM * 1024;
    unsigned short* w1_1t = p; p += 1024 * INDIM;
    unsigned short* w2_1t = p; p += INDIM * 1024;
    unsigned short* w1_2t = p; p += 512 * INDIM;
    unsigned short* w2_2t = p; p += INDIM * 512;
    float* part = (float*)p;                                 // [2][4096,512] fp32

    // 0) all weight transposes in ONE launch (z = weight index)
    transpose_all<<<dim3(26, 26, 6), 256, 0, stream>>>(
        w1_0, w1_0t, w2_0, w2_0t, w1_1, w1_1t, w2_1, w2_1t, w1_2, w1_2t, w2_2, w2_2t);

    // 1) embedding bag -> bf16 feat
    embed_pool<<<BATCH * FEATS / 4, 256, 0, stream>>>(x, emb, feat);

    // 2) residual blocks (R7 GEMM + XCD swizzle; G5 split-K=2 for full-chip grid)
    gemm_bf16<<<dim3(1024/128, BATCH/128), 512, 0, stream>>>(
        feat, w1_0t, b1_0, nullptr, h, nullptr, BATCH, 1024, INDIM, 1);
    gemm_bf16<<<dim3(INDIM/128, BATCH/128), 512, 0, stream>>>(
        h, w2_0t, b2_0, feat, feat, nullptr, BATCH, INDIM, 1024, 1);
    gemm_bf16<<<dim3(1024/128, BATCH/128), 512, 0, stream>>>(
        feat, w1_1t, b1_1, nullptr, h, nullptr, BATCH, 1024, INDIM, 1);
    gemm_bf16<<<dim3(INDIM/128, BATCH/128), 512, 0, stream>>>(
        h, w2_1t, b2_1, feat, feat, nullptr, BATCH, INDIM, 1024, 1);
    gemm_bf16<<<dim3(512/128, BATCH/128, 2), 512, 0, stream>>>(
        feat, w1_2t, b1_2, nullptr, nullptr, part, BATCH, 512, INDIM, 1);
    reduce_split<<<(BATCH * 512 / 4) / 256, 256, 0, stream>>>(
        part, b1_2, h, BATCH, 512);
    gemm_bf16<<<dim3(INDIM/128, BATCH/128), 512, 0, stream>>>(
        h, w2_2t, b2_2, feat, feat, nullptr, BATCH, INDIM, 512, 1);

    // 3) head
    final_head<<<BATCH / 4, 256, 0, stream>>>(feat, linw, linb, out);
}